// Round 8
// baseline (332.235 us; speedup 1.0000x reference)
//
#include <hip/hip_runtime.h>

using bf16x8 = __attribute__((ext_vector_type(8))) short;
using f32x4  = __attribute__((ext_vector_type(4))) float;
using u32x4  = __attribute__((ext_vector_type(4))) unsigned int;
using u32x2  = __attribute__((ext_vector_type(2))) unsigned int;

__device__ __forceinline__ unsigned short f2bf(float f) {
  unsigned int u = __builtin_bit_cast(unsigned int, f);
  u += 0x7FFF + ((u >> 16) & 1);               // RNE
  return (unsigned short)(u >> 16);
}
__device__ __forceinline__ bf16x8 lds_frag(const unsigned short* p) {
  return __builtin_bit_cast(bf16x8, *(const u32x4*)p);
}
__device__ __forceinline__ bf16x8 glb_frag(const unsigned short* p) {
  return __builtin_bit_cast(bf16x8, *(const u32x4*)p);
}
// async global->LDS, 16B per lane; LDS dest = wave-uniform base + lane*16
__device__ __forceinline__ void async_copy16(const unsigned short* g, unsigned short* l) {
  __builtin_amdgcn_global_load_lds(
      (const __attribute__((address_space(1))) unsigned int*)g,
      (__attribute__((address_space(3))) unsigned int*)l, 16, 0, 0);
}

// LDS-tiled transpose+cast: out[c*R+r] = bf16(in[r*C+c]). R,C multiples of 32.
__global__ void transpose_cast_k(const float* __restrict__ in,
                                 unsigned short* __restrict__ out, int R, int C) {
  __shared__ float tile[32][33];
  const int tx = threadIdx.x & 31, ty = threadIdx.x >> 5;   // 32 x 8
  const int c0 = blockIdx.x * 32, r0 = blockIdx.y * 32;
  #pragma unroll
  for (int i = 0; i < 4; ++i)
    tile[ty + i * 8][tx] = in[(size_t)(r0 + ty + i * 8) * C + c0 + tx];
  __syncthreads();
  #pragma unroll
  for (int i = 0; i < 4; ++i)
    out[(size_t)(c0 + ty + i * 8) * R + r0 + tx] = f2bf(tile[tx][ty + i * 8]);
}

// ---------------- GEMM, A = fp32 (fused cast), Bt = bf16 ----------------
// C[M,N] = bf16(A[M,K]) @ Bt[N,K]^T. 128x128 tile, BK=64.
// A: coalesced float4 loads -> RNE cvt -> swizzled ds_write_b64.
// B: global_load_lds. XOR bank swizzle (0 conflicts), XCD M-panel swizzle.
__global__ __launch_bounds__(256, 3)
void gemm_a32_bt(const float* __restrict__ A,
                 const unsigned short* __restrict__ Bt,
                 unsigned short* __restrict__ C,
                 int M, int N, int K, int n_tiles, int mt_per_xcd) {
  __shared__ unsigned short Ash[128 * 64];   // 16 KB
  __shared__ unsigned short Bsh[128 * 64];   // 16 KB
  const int tid  = threadIdx.x;
  const int wv   = tid >> 6, lane = tid & 63;
  const int quad = lane >> 4, l15 = lane & 15;
  const int wr   = wv >> 1, wc = wv & 1;

  const int b = blockIdx.x;
  const int xcd = b & 7, local = b >> 3;
  const int mt = xcd * mt_per_xcd + local / n_tiles;
  const int nt = local % n_tiles;
  const int m0 = mt * 128, n0 = nt * 128;

  // B staging (async): LDS slot lin=(row=lin>>3, cg=lin&7); glb group cg^(row&7)
  const unsigned short* pB[4];
  #pragma unroll
  for (int p = 0; p < 4; ++p) {
    int lin = p * 256 + tid;
    int row = lin >> 3, g = (lin & 7) ^ (row & 7);
    pB[p] = &Bt[(size_t)(n0 + row) * K + g * 8];
  }
  // A staging (fp32 VGPR round-trip): chunk c = p*256+tid, row=c>>4, fq=c&15
  const float* pA[8];
  int dstA[8];
  #pragma unroll
  for (int p = 0; p < 8; ++p) {
    int c = p * 256 + tid;
    int row = c >> 4, fq = c & 15;
    pA[p] = &A[(size_t)(m0 + row) * K + fq * 4];
    dstA[p] = row * 64 + (((fq >> 1) ^ (row & 7)) * 8) + (fq & 1) * 4;
  }

  f32x4 acc[4][4];
  #pragma unroll
  for (int i = 0; i < 4; ++i)
    #pragma unroll
    for (int j = 0; j < 4; ++j)
      acc[i][j] = (f32x4){0.f, 0.f, 0.f, 0.f};

  for (int k0 = 0; k0 < K; k0 += 64) {
    #pragma unroll
    for (int p = 0; p < 4; ++p)
      async_copy16(pB[p] + k0, &Bsh[(p * 256 + tid) * 8]);
    #pragma unroll
    for (int p = 0; p < 8; ++p) {
      f32x4 v = *(const f32x4*)(pA[p] + k0);
      unsigned int lo = (unsigned int)f2bf(v[0]) | ((unsigned int)f2bf(v[1]) << 16);
      unsigned int hi = (unsigned int)f2bf(v[2]) | ((unsigned int)f2bf(v[3]) << 16);
      *(u32x2*)&Ash[dstA[p]] = (u32x2){lo, hi};
    }
    __syncthreads();
    #pragma unroll
    for (int ks = 0; ks < 2; ++ks) {
      const int swz = (((ks * 4 + quad) ^ (l15 & 7)) * 8);
      bf16x8 af[4], bfr[4];
      #pragma unroll
      for (int i = 0; i < 4; ++i)
        af[i] = lds_frag(&Ash[(wr * 64 + i * 16 + l15) * 64 + swz]);
      #pragma unroll
      for (int j = 0; j < 4; ++j)
        bfr[j] = lds_frag(&Bsh[(wc * 64 + j * 16 + l15) * 64 + swz]);
      #pragma unroll
      for (int i = 0; i < 4; ++i)
        #pragma unroll
        for (int j = 0; j < 4; ++j)
          acc[i][j] = __builtin_amdgcn_mfma_f32_16x16x32_bf16(af[i], bfr[j], acc[i][j], 0, 0, 0);
    }
    __syncthreads();
  }

  #pragma unroll
  for (int i = 0; i < 4; ++i) {
    #pragma unroll
    for (int j = 0; j < 4; ++j) {
      int col = n0 + wc * 64 + j * 16 + l15;
      #pragma unroll
      for (int r = 0; r < 4; ++r) {
        int row = m0 + wr * 64 + i * 16 + quad * 4 + r;
        C[(size_t)row * N + col] = f2bf(acc[i][j][r]);
      }
    }
  }
}

// ---------------- GEMM, A/Bt bf16 (for out-projection) ----------------
template <typename OutT>
__global__ __launch_bounds__(256, 3)
void gemm_bt(const unsigned short* __restrict__ A,
             const unsigned short* __restrict__ Bt,
             OutT* __restrict__ C,
             const float* __restrict__ bias,
             int M, int N, int K, int n_tiles, int mt_per_xcd) {
  __shared__ unsigned short Ash[128 * 64];   // 16 KB
  __shared__ unsigned short Bsh[128 * 64];   // 16 KB
  const int tid  = threadIdx.x;
  const int wv   = tid >> 6, lane = tid & 63;
  const int quad = lane >> 4, l15 = lane & 15;
  const int wr   = wv >> 1, wc = wv & 1;

  const int b = blockIdx.x;
  const int xcd = b & 7, local = b >> 3;
  const int mt = xcd * mt_per_xcd + local / n_tiles;
  const int nt = local % n_tiles;
  const int m0 = mt * 128, n0 = nt * 128;

  const unsigned short* pA[4];
  const unsigned short* pB[4];
  #pragma unroll
  for (int p = 0; p < 4; ++p) {
    int lin = p * 256 + tid;
    int row = lin >> 3, g = (lin & 7) ^ (row & 7);
    pA[p] = &A[(size_t)(m0 + row) * K + g * 8];
    pB[p] = &Bt[(size_t)(n0 + row) * K + g * 8];
  }

  f32x4 acc[4][4];
  #pragma unroll
  for (int i = 0; i < 4; ++i)
    #pragma unroll
    for (int j = 0; j < 4; ++j)
      acc[i][j] = (f32x4){0.f, 0.f, 0.f, 0.f};

  for (int k0 = 0; k0 < K; k0 += 64) {
    #pragma unroll
    for (int p = 0; p < 4; ++p)
      async_copy16(pA[p] + k0, &Ash[(p * 256 + tid) * 8]);
    #pragma unroll
    for (int p = 0; p < 4; ++p)
      async_copy16(pB[p] + k0, &Bsh[(p * 256 + tid) * 8]);
    __syncthreads();
    #pragma unroll
    for (int ks = 0; ks < 2; ++ks) {
      const int swz = (((ks * 4 + quad) ^ (l15 & 7)) * 8);
      bf16x8 af[4], bfr[4];
      #pragma unroll
      for (int i = 0; i < 4; ++i)
        af[i] = lds_frag(&Ash[(wr * 64 + i * 16 + l15) * 64 + swz]);
      #pragma unroll
      for (int j = 0; j < 4; ++j)
        bfr[j] = lds_frag(&Bsh[(wc * 64 + j * 16 + l15) * 64 + swz]);
      #pragma unroll
      for (int i = 0; i < 4; ++i)
        #pragma unroll
        for (int j = 0; j < 4; ++j)
          acc[i][j] = __builtin_amdgcn_mfma_f32_16x16x32_bf16(af[i], bfr[j], acc[i][j], 0, 0, 0);
    }
    __syncthreads();
  }

  #pragma unroll
  for (int i = 0; i < 4; ++i) {
    #pragma unroll
    for (int j = 0; j < 4; ++j) {
      int col = n0 + wc * 64 + j * 16 + l15;
      float badd = (bias != nullptr) ? bias[col] : 0.f;
      #pragma unroll
      for (int r = 0; r < 4; ++r) {
        int row = m0 + wr * 64 + i * 16 + quad * 4 + r;
        if constexpr (sizeof(OutT) == 2)
          C[(size_t)row * N + col] = f2bf(acc[i][j][r] + badd);
        else
          C[(size_t)row * N + col] = acc[i][j][r] + badd;
      }
    }
  }
}

// Local attention v3: one block per (head, window), 256 threads.
// Ksh [tok(256)][feat(64), XOR-swizzled 16B groups] -> coalesced stage,
//   conflict-free b128 frag reads (gemm-verified pattern).
// VshT [feat(64)][tok(256), XOR-swizzled] -> conflict-free PV B-frags.
// Per-wave private P ping-pong, no barriers in the P round-trip.
// Mask-skip: row-tile t computes nt <= t+8, ks <= (t+8)/2.
// LDS = 72 KB -> 2 blocks/CU.
__global__ __launch_bounds__(256, 2)
void attn_local(const unsigned short* __restrict__ qkv,
                unsigned short* __restrict__ out) {
  __shared__ unsigned short Ksh[256 * 64];    // 32 KB
  __shared__ unsigned short VshT[64 * 256];   // 32 KB
  __shared__ unsigned short Psh[4 * 1024];    // 8 KB

  const int tid  = threadIdx.x;
  const int wv   = tid >> 6, lane = tid & 63;
  const int quad = lane >> 4, l15 = lane & 15;
  const int h = blockIdx.x & 7, w = blockIdx.x >> 3;
  const int tok0 = (w - 1) * 128;
  const unsigned short* kplane = qkv + 512 + h * 64;
  const unsigned short* vplane = qkv + 1024 + h * 64;
  const unsigned short* qplane = qkv + h * 64;

  // ---- stage K: coalesced loads, swizzled stores; zeros for w==0 pad ----
  #pragma unroll
  for (int p = 0; p < 8; ++p) {
    int c = p * 256 + tid;                 // 2048 = 256 toks x 8 groups
    int j = c >> 3, sub = c & 7;
    u32x4 kvv = (u32x4){0, 0, 0, 0};
    if (!(w == 0 && j < 128))
      kvv = *(const u32x4*)&kplane[(size_t)(tok0 + j) * 1536 + sub * 8];
    *(u32x4*)&Ksh[j * 64 + ((sub ^ (j & 7)) * 8)] = kvv;
  }
  // ---- stage V^T ----
  {
    const int n = tid & 63, kb4 = tid >> 6;
    #pragma unroll
    for (int kk = 0; kk < 8; ++kk) {
      int kb = kk * 4 + kb4;               // token 16B-group
      unsigned short tmp[8];
      if (w == 0 && kb < 16) {
        #pragma unroll
        for (int j = 0; j < 8; ++j) tmp[j] = 0;
      } else {
        #pragma unroll
        for (int j = 0; j < 8; ++j)
          tmp[j] = vplane[(size_t)(tok0 + kb * 8 + j) * 1536 + n];
      }
      *(u32x4*)&VshT[n * 256 + ((kb ^ (n & 7)) * 8)] = *(u32x4*)tmp;
    }
  }
  __syncthreads();

  unsigned short* Pw = &Psh[wv * 1024];

  #pragma unroll
  for (int mt = 0; mt < 2; ++mt) {
    const int t = wv * 2 + mt;             // row-tile 0..7
    const int ntmax = t + 8;
    const int rowb = t * 16;

    bf16x8 qf[2];
    {
      const unsigned short* qp = &qplane[(size_t)(w * 128 + rowb + l15) * 1536];
      qf[0] = glb_frag(&qp[quad * 8]);
      qf[1] = glb_frag(&qp[32 + quad * 8]);
    }

    // ---- scores from Ksh (conflict-free b128) ----
    float s[16][4];
    #pragma unroll
    for (int nt = 0; nt < 16; ++nt) {
      if (nt <= ntmax) {
        const int row = nt * 16 + l15;
        bf16x8 kf0 = lds_frag(&Ksh[row * 64 + ((quad ^ (l15 & 7)) * 8)]);
        bf16x8 kf1 = lds_frag(&Ksh[row * 64 + (((4 + quad) ^ (l15 & 7)) * 8)]);
        f32x4 a = (f32x4){0.f, 0.f, 0.f, 0.f};
        a = __builtin_amdgcn_mfma_f32_16x16x32_bf16(qf[0], kf0, a, 0, 0, 0);
        a = __builtin_amdgcn_mfma_f32_16x16x32_bf16(qf[1], kf1, a, 0, 0, 0);
        #pragma unroll
        for (int r = 0; r < 4; ++r) s[nt][r] = a[r];
      }
    }

    // ---- masked softmax (row = rowb + quad*4 + r, col = nt*16 + l15) ----
    #pragma unroll
    for (int r = 0; r < 4; ++r) {
      int lim = rowb + quad * 4 + r + 128;
      float mx = -3.0e38f;
      #pragma unroll
      for (int nt = 0; nt < 16; ++nt) {
        if (nt <= ntmax) {
          float v = ((nt * 16 + l15) <= lim) ? s[nt][r] * 0.125f : -3.0e38f;
          s[nt][r] = v;
          mx = fmaxf(mx, v);
        }
      }
      mx = fmaxf(mx, __shfl_xor(mx, 1));
      mx = fmaxf(mx, __shfl_xor(mx, 2));
      mx = fmaxf(mx, __shfl_xor(mx, 4));
      mx = fmaxf(mx, __shfl_xor(mx, 8));
      float sum = 0.f;
      #pragma unroll
      for (int nt = 0; nt < 16; ++nt) {
        if (nt <= ntmax) {
          float p = __expf(s[nt][r] - mx);
          s[nt][r] = p;
          sum += p;
        }
      }
      sum += __shfl_xor(sum, 1);
      sum += __shfl_xor(sum, 2);
      sum += __shfl_xor(sum, 4);
      sum += __shfl_xor(sum, 8);
      float inv = 1.f / sum;
      #pragma unroll
      for (int nt = 0; nt < 16; ++nt)
        if (nt <= ntmax) s[nt][r] *= inv;
    }

    // ---- PV: wave-private P ping-pong (no barriers), mask-skip on ks ----
    f32x4 o[4];
    #pragma unroll
    for (int n2 = 0; n2 < 4; ++n2) o[n2] = (f32x4){0.f, 0.f, 0.f, 0.f};
    const int ksmax = ntmax >> 1;
    #pragma unroll
    for (int ks = 0; ks < 8; ++ks) {
      if (ks <= ksmax) {
        unsigned short* pp = Pw + (ks & 1) * 512;
        #pragma unroll
        for (int half = 0; half < 2; ++half) {
          int nt = ks * 2 + half;
          #pragma unroll
          for (int r = 0; r < 4; ++r) {
            int row = quad * 4 + r;
            int g = (half * 2 + (l15 >> 3) + quad) & 3;
            pp[row * 32 + g * 8 + (l15 & 7)] =
                (nt <= ntmax) ? f2bf(s[nt][r]) : (unsigned short)0;
          }
        }
        bf16x8 pa = lds_frag(&pp[l15 * 32 + (((quad + (l15 >> 2)) & 3) * 8)]);
        #pragma unroll
        for (int n2 = 0; n2 < 4; ++n2) {
          int f = n2 * 16 + l15;
          bf16x8 vb = lds_frag(&VshT[f * 256 + (((ks * 4 + quad) ^ (f & 7)) * 8)]);
          o[n2] = __builtin_amdgcn_mfma_f32_16x16x32_bf16(pa, vb, o[n2], 0, 0, 0);
        }
      }
    }

    int tokb = w * 128 + rowb + quad * 4;
    #pragma unroll
    for (int n2 = 0; n2 < 4; ++n2)
      #pragma unroll
      for (int r = 0; r < 4; ++r)
        out[(size_t)(tokb + r) * 512 + h * 64 + n2 * 16 + l15] = f2bf(o[n2][r]);
  }
}

extern "C" void kernel_launch(void* const* d_in, const int* in_sizes, int n_in,
                              void* d_out, int out_size, void* d_ws, size_t ws_size,
                              hipStream_t stream) {
  const float* x     = (const float*)d_in[0];  // 16384 x 1024 fp32
  const float* w_qkv = (const float*)d_in[1];  // 1024 x 1536 fp32
  const float* w_out = (const float*)d_in[2];  // 512 x 1024 fp32
  const float* b_out = (const float*)d_in[3];  // 1024 fp32
  float* out = (float*)d_out;                  // 16384 x 1024 fp32

  char* ws = (char*)d_ws;
  unsigned short* wqkvT = (unsigned short*)ws;                     // 1536x1024 (3 MB)
  unsigned short* woutT = (unsigned short*)(ws + 3145728);         // 1024x512  (1 MB)
  unsigned short* qkv   = (unsigned short*)(ws + 4194304);         // 16384x1536 (48 MB)
  unsigned short* attno = (unsigned short*)(ws + 54525952);        // 16384x512 (16 MB)

  transpose_cast_k<<<dim3(48, 32), 256, 0, stream>>>(w_qkv, wqkvT, 1024, 1536);
  transpose_cast_k<<<dim3(32, 16), 256, 0, stream>>>(w_out, woutT, 512, 1024);
  // QKV projection (fused fp32->bf16 A-cast): 128 m-tiles x 12 n-tiles
  gemm_a32_bt<<<1536, 256, 0, stream>>>(
      x, wqkvT, qkv, 16384, 1536, 1024, 12, 16);
  attn_local<<<1024, 256, 0, stream>>>(qkv, attno);
  // out-projection: 128 m-tiles x 8 n-tiles
  gemm_bt<float><<<1024, 256, 0, stream>>>(
      attno, woutT, out, b_out, 16384, 1024, 512, 8, 16);
}

// Round 9
// 238.755 us; speedup vs baseline: 1.3915x; 1.3915x over previous
//
#include <hip/hip_runtime.h>

using bf16x8 = __attribute__((ext_vector_type(8))) short;
using f32x4  = __attribute__((ext_vector_type(4))) float;
using u32x4  = __attribute__((ext_vector_type(4))) unsigned int;

__device__ __forceinline__ unsigned short f2bf(float f) {
  unsigned int u = __builtin_bit_cast(unsigned int, f);
  u += 0x7FFF + ((u >> 16) & 1);               // RNE
  return (unsigned short)(u >> 16);
}
__device__ __forceinline__ bf16x8 lds_frag(const unsigned short* p) {
  return __builtin_bit_cast(bf16x8, *(const u32x4*)p);
}
__device__ __forceinline__ bf16x8 glb_frag(const unsigned short* p) {
  return __builtin_bit_cast(bf16x8, *(const u32x4*)p);
}
// async global->LDS, 16B per lane; LDS dest = wave-uniform base + lane*16
__device__ __forceinline__ void async_copy16(const unsigned short* g, unsigned short* l) {
  __builtin_amdgcn_global_load_lds(
      (const __attribute__((address_space(1))) unsigned int*)g,
      (__attribute__((address_space(3))) unsigned int*)l, 16, 0, 0);
}

// fp32 -> bf16 elementwise, 8 elems/thread
__global__ void cast_bf16_k(const float* __restrict__ in,
                            unsigned short* __restrict__ out, int n) {
  int i = (blockIdx.x * 256 + threadIdx.x) * 8;
  if (i < n) {
    unsigned short r[8];
    #pragma unroll
    for (int j = 0; j < 8; ++j) r[j] = f2bf(in[i + j]);
    *(u32x4*)&out[i] = *(u32x4*)r;
  }
}

// LDS-tiled transpose+cast: out[c*R+r] = bf16(in[r*C+c]). R,C multiples of 32.
__global__ void transpose_cast_k(const float* __restrict__ in,
                                 unsigned short* __restrict__ out, int R, int C) {
  __shared__ float tile[32][33];
  const int tx = threadIdx.x & 31, ty = threadIdx.x >> 5;   // 32 x 8
  const int c0 = blockIdx.x * 32, r0 = blockIdx.y * 32;
  #pragma unroll
  for (int i = 0; i < 4; ++i)
    tile[ty + i * 8][tx] = in[(size_t)(r0 + ty + i * 8) * C + c0 + tx];
  __syncthreads();
  #pragma unroll
  for (int i = 0; i < 4; ++i)
    out[(size_t)(c0 + ty + i * 8) * R + r0 + tx] = f2bf(tile[tx][ty + i * 8]);
}

// ---------------- QKV GEMM: A/Bt bf16, C bf16 ----------------
// 128x128 tile, BK=64, global_load_lds staging, XOR bank swizzle (0 conflicts),
// XCD M-panel swizzle (FETCH 137->42 MB). ~912 TF (m97-structure plateau).
__global__ __launch_bounds__(256, 3)
void gemm_bt(const unsigned short* __restrict__ A,
             const unsigned short* __restrict__ Bt,
             unsigned short* __restrict__ C,
             int M, int N, int K, int n_tiles, int mt_per_xcd) {
  __shared__ unsigned short Ash[128 * 64];   // 16 KB
  __shared__ unsigned short Bsh[128 * 64];   // 16 KB
  const int tid  = threadIdx.x;
  const int wv   = tid >> 6, lane = tid & 63;
  const int quad = lane >> 4, l15 = lane & 15;
  const int wr   = wv >> 1, wc = wv & 1;

  const int b = blockIdx.x;
  const int xcd = b & 7, local = b >> 3;
  const int mt = xcd * mt_per_xcd + local / n_tiles;
  const int nt = local % n_tiles;
  const int m0 = mt * 128, n0 = nt * 128;

  const unsigned short* pA[4];
  const unsigned short* pB[4];
  #pragma unroll
  for (int p = 0; p < 4; ++p) {
    int lin = p * 256 + tid;
    int row = lin >> 3, g = (lin & 7) ^ (row & 7);
    pA[p] = &A[(size_t)(m0 + row) * K + g * 8];
    pB[p] = &Bt[(size_t)(n0 + row) * K + g * 8];
  }

  f32x4 acc[4][4];
  #pragma unroll
  for (int i = 0; i < 4; ++i)
    #pragma unroll
    for (int j = 0; j < 4; ++j)
      acc[i][j] = (f32x4){0.f, 0.f, 0.f, 0.f};

  for (int k0 = 0; k0 < K; k0 += 64) {
    #pragma unroll
    for (int p = 0; p < 4; ++p)
      async_copy16(pA[p] + k0, &Ash[(p * 256 + tid) * 8]);
    #pragma unroll
    for (int p = 0; p < 4; ++p)
      async_copy16(pB[p] + k0, &Bsh[(p * 256 + tid) * 8]);
    __syncthreads();
    #pragma unroll
    for (int ks = 0; ks < 2; ++ks) {
      const int swz = (((ks * 4 + quad) ^ (l15 & 7)) * 8);
      bf16x8 af[4], bfr[4];
      #pragma unroll
      for (int i = 0; i < 4; ++i)
        af[i] = lds_frag(&Ash[(wr * 64 + i * 16 + l15) * 64 + swz]);
      #pragma unroll
      for (int j = 0; j < 4; ++j)
        bfr[j] = lds_frag(&Bsh[(wc * 64 + j * 16 + l15) * 64 + swz]);
      #pragma unroll
      for (int i = 0; i < 4; ++i)
        #pragma unroll
        for (int j = 0; j < 4; ++j)
          acc[i][j] = __builtin_amdgcn_mfma_f32_16x16x32_bf16(af[i], bfr[j], acc[i][j], 0, 0, 0);
    }
    __syncthreads();
  }

  #pragma unroll
  for (int i = 0; i < 4; ++i) {
    #pragma unroll
    for (int j = 0; j < 4; ++j) {
      int col = n0 + wc * 64 + j * 16 + l15;
      #pragma unroll
      for (int r = 0; r < 4; ++r) {
        int row = m0 + wr * 64 + i * 16 + quad * 4 + r;
        C[(size_t)row * N + col] = f2bf(acc[i][j][r]);
      }
    }
  }
}

// ---------------- out-proj GEMM: A/Bt bf16, C fp32 + bias ----------------
// Distinct name so rocprof top-5 can tell it from the QKV gemm.
__global__ __launch_bounds__(256, 3)
void gemm_out_f32(const unsigned short* __restrict__ A,
                  const unsigned short* __restrict__ Bt,
                  float* __restrict__ C,
                  const float* __restrict__ bias,
                  int M, int N, int K, int n_tiles, int mt_per_xcd) {
  __shared__ unsigned short Ash[128 * 64];   // 16 KB
  __shared__ unsigned short Bsh[128 * 64];   // 16 KB
  const int tid  = threadIdx.x;
  const int wv   = tid >> 6, lane = tid & 63;
  const int quad = lane >> 4, l15 = lane & 15;
  const int wr   = wv >> 1, wc = wv & 1;

  const int b = blockIdx.x;
  const int xcd = b & 7, local = b >> 3;
  const int mt = xcd * mt_per_xcd + local / n_tiles;
  const int nt = local % n_tiles;
  const int m0 = mt * 128, n0 = nt * 128;

  const unsigned short* pA[4];
  const unsigned short* pB[4];
  #pragma unroll
  for (int p = 0; p < 4; ++p) {
    int lin = p * 256 + tid;
    int row = lin >> 3, g = (lin & 7) ^ (row & 7);
    pA[p] = &A[(size_t)(m0 + row) * K + g * 8];
    pB[p] = &Bt[(size_t)(n0 + row) * K + g * 8];
  }

  f32x4 acc[4][4];
  #pragma unroll
  for (int i = 0; i < 4; ++i)
    #pragma unroll
    for (int j = 0; j < 4; ++j)
      acc[i][j] = (f32x4){0.f, 0.f, 0.f, 0.f};

  for (int k0 = 0; k0 < K; k0 += 64) {
    #pragma unroll
    for (int p = 0; p < 4; ++p)
      async_copy16(pA[p] + k0, &Ash[(p * 256 + tid) * 8]);
    #pragma unroll
    for (int p = 0; p < 4; ++p)
      async_copy16(pB[p] + k0, &Bsh[(p * 256 + tid) * 8]);
    __syncthreads();
    #pragma unroll
    for (int ks = 0; ks < 2; ++ks) {
      const int swz = (((ks * 4 + quad) ^ (l15 & 7)) * 8);
      bf16x8 af[4], bfr[4];
      #pragma unroll
      for (int i = 0; i < 4; ++i)
        af[i] = lds_frag(&Ash[(wr * 64 + i * 16 + l15) * 64 + swz]);
      #pragma unroll
      for (int j = 0; j < 4; ++j)
        bfr[j] = lds_frag(&Bsh[(wc * 64 + j * 16 + l15) * 64 + swz]);
      #pragma unroll
      for (int i = 0; i < 4; ++i)
        #pragma unroll
        for (int j = 0; j < 4; ++j)
          acc[i][j] = __builtin_amdgcn_mfma_f32_16x16x32_bf16(af[i], bfr[j], acc[i][j], 0, 0, 0);
    }
    __syncthreads();
  }

  #pragma unroll
  for (int i = 0; i < 4; ++i) {
    #pragma unroll
    for (int j = 0; j < 4; ++j) {
      int col = n0 + wc * 64 + j * 16 + l15;
      float badd = bias[col];
      #pragma unroll
      for (int r = 0; r < 4; ++r) {
        int row = m0 + wr * 64 + i * 16 + quad * 4 + r;
        C[(size_t)row * N + col] = acc[i][j][r] + badd;
      }
    }
  }
}

// Local attention v3: one block per (head, window), 256 threads.
// Ksh [tok(256)][feat, XOR-swizzled] coalesced stage, conflict-free b128 reads.
// VshT [feat(64)][tok, XOR-swizzled]. Wave-private P ping-pong (no barriers).
// Mask-skip: row-tile t computes nt <= t+8, ks <= (t+8)/2. LDS 72 KB.
__global__ __launch_bounds__(256, 2)
void attn_local(const unsigned short* __restrict__ qkv,
                unsigned short* __restrict__ out) {
  __shared__ unsigned short Ksh[256 * 64];    // 32 KB
  __shared__ unsigned short VshT[64 * 256];   // 32 KB
  __shared__ unsigned short Psh[4 * 1024];    // 8 KB

  const int tid  = threadIdx.x;
  const int wv   = tid >> 6, lane = tid & 63;
  const int quad = lane >> 4, l15 = lane & 15;
  const int h = blockIdx.x & 7, w = blockIdx.x >> 3;
  const int tok0 = (w - 1) * 128;
  const unsigned short* kplane = qkv + 512 + h * 64;
  const unsigned short* vplane = qkv + 1024 + h * 64;
  const unsigned short* qplane = qkv + h * 64;

  #pragma unroll
  for (int p = 0; p < 8; ++p) {
    int c = p * 256 + tid;                 // 2048 = 256 toks x 8 groups
    int j = c >> 3, sub = c & 7;
    u32x4 kvv = (u32x4){0, 0, 0, 0};
    if (!(w == 0 && j < 128))
      kvv = *(const u32x4*)&kplane[(size_t)(tok0 + j) * 1536 + sub * 8];
    *(u32x4*)&Ksh[j * 64 + ((sub ^ (j & 7)) * 8)] = kvv;
  }
  {
    const int n = tid & 63, kb4 = tid >> 6;
    #pragma unroll
    for (int kk = 0; kk < 8; ++kk) {
      int kb = kk * 4 + kb4;               // token 16B-group
      unsigned short tmp[8];
      if (w == 0 && kb < 16) {
        #pragma unroll
        for (int j = 0; j < 8; ++j) tmp[j] = 0;
      } else {
        #pragma unroll
        for (int j = 0; j < 8; ++j)
          tmp[j] = vplane[(size_t)(tok0 + kb * 8 + j) * 1536 + n];
      }
      *(u32x4*)&VshT[n * 256 + ((kb ^ (n & 7)) * 8)] = *(u32x4*)tmp;
    }
  }
  __syncthreads();

  unsigned short* Pw = &Psh[wv * 1024];

  #pragma unroll
  for (int mt = 0; mt < 2; ++mt) {
    const int t = wv * 2 + mt;             // row-tile 0..7
    const int ntmax = t + 8;
    const int rowb = t * 16;

    bf16x8 qf[2];
    {
      const unsigned short* qp = &qplane[(size_t)(w * 128 + rowb + l15) * 1536];
      qf[0] = glb_frag(&qp[quad * 8]);
      qf[1] = glb_frag(&qp[32 + quad * 8]);
    }

    float s[16][4];
    #pragma unroll
    for (int nt = 0; nt < 16; ++nt) {
      if (nt <= ntmax) {
        const int row = nt * 16 + l15;
        bf16x8 kf0 = lds_frag(&Ksh[row * 64 + ((quad ^ (l15 & 7)) * 8)]);
        bf16x8 kf1 = lds_frag(&Ksh[row * 64 + (((4 + quad) ^ (l15 & 7)) * 8)]);
        f32x4 a = (f32x4){0.f, 0.f, 0.f, 0.f};
        a = __builtin_amdgcn_mfma_f32_16x16x32_bf16(qf[0], kf0, a, 0, 0, 0);
        a = __builtin_amdgcn_mfma_f32_16x16x32_bf16(qf[1], kf1, a, 0, 0, 0);
        #pragma unroll
        for (int r = 0; r < 4; ++r) s[nt][r] = a[r];
      }
    }

    #pragma unroll
    for (int r = 0; r < 4; ++r) {
      int lim = rowb + quad * 4 + r + 128;
      float mx = -3.0e38f;
      #pragma unroll
      for (int nt = 0; nt < 16; ++nt) {
        if (nt <= ntmax) {
          float v = ((nt * 16 + l15) <= lim) ? s[nt][r] * 0.125f : -3.0e38f;
          s[nt][r] = v;
          mx = fmaxf(mx, v);
        }
      }
      mx = fmaxf(mx, __shfl_xor(mx, 1));
      mx = fmaxf(mx, __shfl_xor(mx, 2));
      mx = fmaxf(mx, __shfl_xor(mx, 4));
      mx = fmaxf(mx, __shfl_xor(mx, 8));
      float sum = 0.f;
      #pragma unroll
      for (int nt = 0; nt < 16; ++nt) {
        if (nt <= ntmax) {
          float p = __expf(s[nt][r] - mx);
          s[nt][r] = p;
          sum += p;
        }
      }
      sum += __shfl_xor(sum, 1);
      sum += __shfl_xor(sum, 2);
      sum += __shfl_xor(sum, 4);
      sum += __shfl_xor(sum, 8);
      float inv = 1.f / sum;
      #pragma unroll
      for (int nt = 0; nt < 16; ++nt)
        if (nt <= ntmax) s[nt][r] *= inv;
    }

    f32x4 o[4];
    #pragma unroll
    for (int n2 = 0; n2 < 4; ++n2) o[n2] = (f32x4){0.f, 0.f, 0.f, 0.f};
    const int ksmax = ntmax >> 1;
    #pragma unroll
    for (int ks = 0; ks < 8; ++ks) {
      if (ks <= ksmax) {
        unsigned short* pp = Pw + (ks & 1) * 512;
        #pragma unroll
        for (int half = 0; half < 2; ++half) {
          int nt = ks * 2 + half;
          #pragma unroll
          for (int r = 0; r < 4; ++r) {
            int row = quad * 4 + r;
            int g = (half * 2 + (l15 >> 3) + quad) & 3;
            pp[row * 32 + g * 8 + (l15 & 7)] =
                (nt <= ntmax) ? f2bf(s[nt][r]) : (unsigned short)0;
          }
        }
        bf16x8 pa = lds_frag(&pp[l15 * 32 + (((quad + (l15 >> 2)) & 3) * 8)]);
        #pragma unroll
        for (int n2 = 0; n2 < 4; ++n2) {
          int f = n2 * 16 + l15;
          bf16x8 vb = lds_frag(&VshT[f * 256 + (((ks * 4 + quad) ^ (f & 7)) * 8)]);
          o[n2] = __builtin_amdgcn_mfma_f32_16x16x32_bf16(pa, vb, o[n2], 0, 0, 0);
        }
      }
    }

    int tokb = w * 128 + rowb + quad * 4;
    #pragma unroll
    for (int n2 = 0; n2 < 4; ++n2)
      #pragma unroll
      for (int r = 0; r < 4; ++r)
        out[(size_t)(tokb + r) * 512 + h * 64 + n2 * 16 + l15] = f2bf(o[n2][r]);
  }
}

extern "C" void kernel_launch(void* const* d_in, const int* in_sizes, int n_in,
                              void* d_out, int out_size, void* d_ws, size_t ws_size,
                              hipStream_t stream) {
  const float* x     = (const float*)d_in[0];  // 16384 x 1024 fp32
  const float* w_qkv = (const float*)d_in[1];  // 1024 x 1536 fp32
  const float* w_out = (const float*)d_in[2];  // 512 x 1024 fp32
  const float* b_out = (const float*)d_in[3];  // 1024 fp32
  float* out = (float*)d_out;                  // 16384 x 1024 fp32

  char* ws = (char*)d_ws;
  unsigned short* xb    = (unsigned short*)ws;                     // 16384x1024 bf16 (32 MB)
  unsigned short* wqkvT = (unsigned short*)(ws + 33554432);        // 1536x1024 (3 MB)
  unsigned short* woutT = (unsigned short*)(ws + 36700160);        // 1024x512  (1 MB)
  unsigned short* qkv   = (unsigned short*)(ws + 37748736);        // 16384x1536 (48 MB)
  unsigned short* attno = (unsigned short*)(ws + 88080384);        // 16384x512 (16 MB)

  cast_bf16_k<<<8192, 256, 0, stream>>>(x, xb, 16384 * 1024);
  transpose_cast_k<<<dim3(48, 32), 256, 0, stream>>>(w_qkv, wqkvT, 1024, 1536);
  transpose_cast_k<<<dim3(32, 16), 256, 0, stream>>>(w_out, woutT, 512, 1024);
  // QKV: 128 m-tiles x 12 n-tiles; 16 m-tiles per xcd
  gemm_bt<<<1536, 256, 0, stream>>>(
      xb, wqkvT, qkv, 16384, 1536, 1024, 12, 16);
  attn_local<<<1024, 256, 0, stream>>>(qkv, attno);
  // out-proj: 128 m-tiles x 8 n-tiles; 16 m-tiles per xcd
  gemm_out_f32<<<1024, 256, 0, stream>>>(
      attno, woutT, out, b_out, 16384, 1024, 512, 8, 16);
}